// Round 7
// baseline (322.939 us; speedup 1.0000x reference)
//
#include <hip/hip_runtime.h>
#include <math.h>

// Problem constants (B,S,D,H) = (8, 2048, 1024, 4), HD = 256
#define BB 8
#define SS 2048
#define DD 1024
#define HH 4
#define HDD 256
#define NROW (BB*SS)           // 16384

// ---------------- fused config (PLAIN launch; co-residency by capacity:
// 512 blocks @ __launch_bounds__(256,2) on 256 CUs => all resident) -------
#define GG 32                  // rows per block
#define NBLK (NROW/GG)         // 512 blocks

// ws layout (float offsets), ~66 KB cleared per launch
#define OFF_TG    0                    // [B][D] atomic-accumulated text-global
#define OFF_IG    (BB*DD)              // [B][D]
#define OFF_SIM   (2*BB*DD)            // [B]
#define OFF_LOGIT (OFF_SIM + BB)       // [B]
#define OFF_CNT   (OFF_LOGIT + BB)     // 2 ints (c1, c2)
#define WS_CLEAR  (OFF_CNT + 2)

__device__ __forceinline__ float wred(float v) {
#pragma unroll
  for (int m = 32; m > 0; m >>= 1) v += __shfl_xor(v, m, 64);
  return v;
}
__device__ __forceinline__ float hsum(const float4 v) { return v.x+v.y+v.z+v.w; }
__device__ __forceinline__ float hsq(const float4 v)  { return v.x*v.x+v.y*v.y+v.z*v.z+v.w*v.w; }
__device__ __forceinline__ float hdot(const float4 a, const float4 b) {
  return a.x*b.x + a.y*b.y + a.z*b.z + a.w*b.w;
}

// =====================================================================
// Fused kernel (round-3 structure, best measured: 185 us), launched as a
// REGULAR kernel so it survives hipGraph capture (cooperative launches
// fail under capture -> previous rounds' timed path silently ran the old
// 4-kernel chain).  Sync via flag barriers:
//   Phase 1 (512 blocks): wave-per-row stats (prefetched), LDS-combine,
//            atomicAdd into TG/IG/SIM.  arrive c1.
//   Gates  (blocks 0..255): spin c1==512, fence, dot TG/IG with Wa/Wq,
//            atomicAdd LOGIT.  arrive c2.
//   Blend  (all blocks): spin c2==256, fence, sigmoid(logit), blend own
//            32 rows using LDS-resident mu/rs.
// Deadlock-free because all 512 blocks are co-resident by capacity.
// =====================================================================
__global__ __launch_bounds__(256, 2) void fused(
    const float* __restrict__ text, const float* __restrict__ image,
    const float* __restrict__ wt, const float* __restrict__ bt,
    const float* __restrict__ wi, const float* __restrict__ bi,
    const float* __restrict__ Wa, const float* __restrict__ Wab,
    const float* __restrict__ Wq, const float* __restrict__ Wqb,
    const float* __restrict__ simw, const float* __restrict__ simb,
    const float* __restrict__ fcw, const float* __restrict__ fcb,
    float* __restrict__ ws, float* __restrict__ out)
{
  const int blk  = blockIdx.x;
  const int tid  = threadIdx.x;
  const int lane = tid & 63;
  const int wv   = tid >> 6;
  const int row0 = blk * GG;
  const int b    = blk >> 6;           // 64 blocks per batch

  __shared__ float smu_t[GG], srs_t[GG], smu_i[GG], srs_i[GG];
  __shared__ float sAcc[2][4][DD];     // 32 KB: per-wave global partial combine
  __shared__ float ssim[4];
  __shared__ float red3[4][4][BB];     // gates

  int* c1 = (int*)(ws + OFF_CNT);
  int* c2 = c1 + 1;

  // ---------------- Phase 1: wave-per-row stats, prefetched ----------------
  {
    const int cb = lane << 2;          // col base within each 256-col chunk
    float4 Wt[4], Bt[4], Wi4[4], Bi4[4];
#pragma unroll
    for (int j = 0; j < 4; ++j) {
      Wt[j]  = *(const float4*)(wt + j*256 + cb);
      Bt[j]  = *(const float4*)(bt + j*256 + cb);
      Wi4[j] = *(const float4*)(wi + j*256 + cb);
      Bi4[j] = *(const float4*)(bi + j*256 + cb);
    }
    float4 tga[4], iga[4];
#pragma unroll
    for (int j = 0; j < 4; ++j) {
      tga[j] = make_float4(0.f,0.f,0.f,0.f);
      iga[j] = make_float4(0.f,0.f,0.f,0.f);
    }
    float sim_loc = 0.f;
    const float invD = 1.f/DD;
    const int rbase = row0 + wv*8;     // this wave's 8 rows

    float4 tb[2][4], ib[2][4];         // double-buffered row registers
    {
      const float* tr = text  + (size_t)rbase*DD + cb;
      const float* ir = image + (size_t)rbase*DD + cb;
#pragma unroll
      for (int j = 0; j < 4; ++j) {
        tb[0][j] = *(const float4*)(tr + j*256);
        ib[0][j] = *(const float4*)(ir + j*256);
      }
    }

#pragma unroll 2
    for (int r = 0; r < 8; ++r) {
      const int cur = r & 1, nxt = cur ^ 1;   // compile-time after unroll 2
      if (r < 7) {                     // prefetch next row under this row's work
        const float* tr = text  + (size_t)(rbase + r + 1)*DD + cb;
        const float* ir = image + (size_t)(rbase + r + 1)*DD + cb;
#pragma unroll
        for (int j = 0; j < 4; ++j) {
          tb[nxt][j] = *(const float4*)(tr + j*256);
          ib[nxt][j] = *(const float4*)(ir + j*256);
        }
      }

      float st=0.f, qt=0.f, si=0.f, qi=0.f;
#pragma unroll
      for (int j = 0; j < 4; ++j) {
        st += hsum(tb[cur][j]);  qt += hsq(tb[cur][j]);
        si += hsum(ib[cur][j]);  qi += hsq(ib[cur][j]);
      }
      st = wred(st); qt = wred(qt); si = wred(si); qi = wred(qi);
      const float mt = st*invD, rt = rsqrtf(qt*invD - mt*mt + 1e-5f);
      const float mi = si*invD, ri = rsqrtf(qi*invD - mi*mi + 1e-5f);
      if (lane == 0) {
        smu_t[wv*8+r]=mt; srs_t[wv*8+r]=rt;
        smu_i[wv*8+r]=mi; srs_i[wv*8+r]=ri;
      }

      float dot=0.f, nt=0.f, ni=0.f;
#pragma unroll
      for (int j = 0; j < 4; ++j) {
        float4 tn, iv;
        tn.x = (tb[cur][j].x-mt)*rt*Wt[j].x + Bt[j].x;
        tn.y = (tb[cur][j].y-mt)*rt*Wt[j].y + Bt[j].y;
        tn.z = (tb[cur][j].z-mt)*rt*Wt[j].z + Bt[j].z;
        tn.w = (tb[cur][j].w-mt)*rt*Wt[j].w + Bt[j].w;
        iv.x = (ib[cur][j].x-mi)*ri*Wi4[j].x + Bi4[j].x;
        iv.y = (ib[cur][j].y-mi)*ri*Wi4[j].y + Bi4[j].y;
        iv.z = (ib[cur][j].z-mi)*ri*Wi4[j].z + Bi4[j].z;
        iv.w = (ib[cur][j].w-mi)*ri*Wi4[j].w + Bi4[j].w;
        tga[j].x += tn.x; tga[j].y += tn.y; tga[j].z += tn.z; tga[j].w += tn.w;
        iga[j].x += iv.x; iga[j].y += iv.y; iga[j].z += iv.z; iga[j].w += iv.w;
        dot += hdot(tn, iv); nt += hsq(tn); ni += hsq(iv);
      }
      dot = wred(dot); nt = wred(nt); ni = wred(ni);
      sim_loc += dot / (fmaxf(sqrtf(nt),1e-6f) * fmaxf(sqrtf(ni),1e-6f));
    }

    // Block-combine per-wave global partials in LDS, then atomics into TG/IG.
#pragma unroll
    for (int j = 0; j < 4; ++j) {
      *(float4*)&sAcc[0][wv][j*256 + cb] = tga[j];
      *(float4*)&sAcc[1][wv][j*256 + cb] = iga[j];
    }
    if (lane == 0) ssim[wv] = sim_loc;
    __syncthreads();

    const int c0 = tid << 2;
    float4 vt = make_float4(0.f,0.f,0.f,0.f);
    float4 vi = make_float4(0.f,0.f,0.f,0.f);
#pragma unroll
    for (int w = 0; w < 4; ++w) {
      const float4 a = *(const float4*)&sAcc[0][w][c0];
      vt.x += a.x; vt.y += a.y; vt.z += a.z; vt.w += a.w;
      const float4 e = *(const float4*)&sAcc[1][w][c0];
      vi.x += e.x; vi.y += e.y; vi.z += e.z; vi.w += e.w;
    }
    atomicAdd(&ws[OFF_TG + b*DD + c0 + 0], vt.x);
    atomicAdd(&ws[OFF_TG + b*DD + c0 + 1], vt.y);
    atomicAdd(&ws[OFF_TG + b*DD + c0 + 2], vt.z);
    atomicAdd(&ws[OFF_TG + b*DD + c0 + 3], vt.w);
    atomicAdd(&ws[OFF_IG + b*DD + c0 + 0], vi.x);
    atomicAdd(&ws[OFF_IG + b*DD + c0 + 1], vi.y);
    atomicAdd(&ws[OFF_IG + b*DD + c0 + 2], vi.z);
    atomicAdd(&ws[OFF_IG + b*DD + c0 + 3], vi.w);
    if (tid == 0) {
      atomicAdd(&ws[OFF_SIM + b], ssim[0]+ssim[1]+ssim[2]+ssim[3]);
    }
  }

  // Arrival: atomics drained by the barrier before signaling.
  __syncthreads();
  if (tid == 0) {
    __hip_atomic_fetch_add(c1, 1, __ATOMIC_RELEASE, __HIP_MEMORY_SCOPE_AGENT);
  }

  // ---------------- Gates (blocks 0..255) ----------------
  if (blk < 256) {
    if (tid == 0) {
      while (__hip_atomic_load(c1, __ATOMIC_RELAXED, __HIP_MEMORY_SCOPE_AGENT) < NBLK)
        __builtin_amdgcn_s_sleep(8);
      __threadfence();                 // acquire: see all phase-1 atomics
    }
    __syncthreads();

    const int d0 = tid << 2;
    const int r0 = blk * 4;            // flat (h,k) row base, 0..1023
    for (int rr = 0; rr < 4; ++rr) {
      const int r = r0 + rr;
      const float4 a4 = *(const float4*)(Wa + (size_t)r*DD + d0);
      const float4 q4 = *(const float4*)(Wq + (size_t)r*DD + d0);
      float acc[BB];
#pragma unroll
      for (int bq = 0; bq < BB; ++bq) {
        const float4 t = *(const float4*)(ws + OFF_TG + bq*DD + d0);
        const float4 i = *(const float4*)(ws + OFF_IG + bq*DD + d0);
        acc[bq] = hdot(a4, t) + hdot(q4, i);
      }
#pragma unroll
      for (int bq = 0; bq < BB; ++bq) {
        acc[bq] = wred(acc[bq]);
        if (lane == 0) red3[rr][wv][bq] = acc[bq];
      }
    }
    __syncthreads();
    if (tid < BB) {
      const int bq = tid;
      const float inv = 1.f/SS;
      const float gs = ws[OFF_SIM + bq] * inv;
      float part = 0.f;
#pragma unroll
      for (int rr = 0; rr < 4; ++rr) {
        const int r = r0 + rr;
        const int k = r & 255;
        const float v = (red3[rr][0][bq] + red3[rr][1][bq] + red3[rr][2][bq] + red3[rr][3][bq]) * inv;
        float gate = v + Wab[r] + Wqb[r] + gs*simw[k] + simb[k];
        gate = fmaxf(gate, 0.f);
        part += gate * fcw[r];
      }
      atomicAdd(&ws[OFF_LOGIT + bq], part);
    }
    __syncthreads();                   // drain LOGIT atomics of tid 0..7
    if (tid == 0) {
      __hip_atomic_fetch_add(c2, 1, __ATOMIC_RELEASE, __HIP_MEMORY_SCOPE_AGENT);
    }
  }

  // ---------------- Blend (all blocks) ----------------
  if (tid == 0) {
    while (__hip_atomic_load(c2, __ATOMIC_RELAXED, __HIP_MEMORY_SCOPE_AGENT) < 256)
      __builtin_amdgcn_s_sleep(8);
    __threadfence();                   // acquire: LOGIT visible
  }
  __syncthreads();

  {
    const int d0 = tid << 2;
    const float4 wt4 = *(const float4*)(wt + d0);
    const float4 bt4 = *(const float4*)(bt + d0);
    const float4 wi4 = *(const float4*)(wi + d0);
    const float4 bi4 = *(const float4*)(bi + d0);
    const float g  = 1.f / (1.f + expf(-(ws[OFF_LOGIT + b] + fcb[0])));
    const float gi = 1.f - g;

    float4 tg[2][4], ig[2][4];         // double-buffered 4-row groups
#pragma unroll
    for (int r = 0; r < 4; ++r) {
      tg[0][r] = *(const float4*)(text  + (size_t)(row0+r)*DD + d0);
      ig[0][r] = *(const float4*)(image + (size_t)(row0+r)*DD + d0);
    }
#pragma unroll 2
    for (int gidx = 0; gidx < 8; ++gidx) {
      const int cur = gidx & 1, nxt = cur ^ 1;
      if (gidx < 7) {
        const int nr = row0 + (gidx+1)*4;
#pragma unroll
        for (int r = 0; r < 4; ++r) {
          tg[nxt][r] = *(const float4*)(text  + (size_t)(nr+r)*DD + d0);
          ig[nxt][r] = *(const float4*)(image + (size_t)(nr+r)*DD + d0);
        }
      }
      const int rr = gidx*4;
#pragma unroll
      for (int r = 0; r < 4; ++r) {
        const float mt = smu_t[rr+r], rt = srs_t[rr+r];
        const float mi = smu_i[rr+r], ri = srs_i[rr+r];
        const float gt = g*rt, gii = gi*ri;
        float4 o;
        o.x = gt*(tg[cur][r].x-mt)*wt4.x + g*bt4.x + gii*(ig[cur][r].x-mi)*wi4.x + gi*bi4.x;
        o.y = gt*(tg[cur][r].y-mt)*wt4.y + g*bt4.y + gii*(ig[cur][r].y-mi)*wi4.y + gi*bi4.y;
        o.z = gt*(tg[cur][r].z-mt)*wt4.z + g*bt4.z + gii*(ig[cur][r].z-mi)*wi4.z + gi*bi4.z;
        o.w = gt*(tg[cur][r].w-mt)*wt4.w + g*bt4.w + gii*(ig[cur][r].w-mi)*wi4.w + gi*bi4.w;
        *(float4*)(out + (size_t)(row0+rr+r)*DD + d0) = o;
      }
    }
  }
}

extern "C" void kernel_launch(void* const* d_in, const int* in_sizes, int n_in,
                              void* d_out, int out_size, void* d_ws, size_t ws_size,
                              hipStream_t stream)
{
  const float* text   = (const float*)d_in[0];
  const float* image  = (const float*)d_in[1];
  const float* ln_t_w = (const float*)d_in[2];
  const float* ln_t_b = (const float*)d_in[3];
  const float* ln_i_w = (const float*)d_in[4];
  const float* ln_i_b = (const float*)d_in[5];
  const float* Wa     = (const float*)d_in[6];
  const float* Wab    = (const float*)d_in[7];
  const float* Wq     = (const float*)d_in[8];
  const float* Wqb    = (const float*)d_in[9];
  const float* simw   = (const float*)d_in[10];
  const float* simb   = (const float*)d_in[11];
  const float* fcw    = (const float*)d_in[12];
  const float* fcb    = (const float*)d_in[13];
  float* ws  = (float*)d_ws;
  float* out = (float*)d_out;

  // Zero TG/IG/SIM accumulators + LOGIT + barrier counters (~66 KB).
  hipMemsetAsync(ws, 0, WS_CLEAR * sizeof(float), stream);

  // PLAIN launch (graph-capture safe). Co-residency of all 512 blocks is
  // guaranteed by capacity: __launch_bounds__(256,2) on 256 CUs.
  fused<<<dim3(NBLK), dim3(256), 0, stream>>>(
      text, image, ln_t_w, ln_t_b, ln_i_w, ln_i_b,
      Wa, Wab, Wq, Wqb, simw, simb, fcw, fcb, ws, out);
}